// Round 17
// baseline (340.820 us; speedup 1.0000x reference)
//
#include <hip/hip_runtime.h>
#include <stdint.h>

// ---------------------------------------------------------------------------
// NonLocalBlockND: B=8, C_IN=256, C_INTER=128, H=W=128, P=16 -> tokens 256/batch,
// token dim D = 128*64 = 8192 (d = c*64 + s, s = u*8+v within 8x8 patch).
// Pipeline:
//   K1 prep   : weights -> bf16 (A-fragment swizzled, hi/lo split) + zero stats
//   K2 proj   : ONE token/block, 512 thr (8 waves), 64KB LDS single-phase
//   K3 qk     : f = theta . phi (3-term split MFMA), K-split 8 (BK=1024),
//               512-thr blocks (8 waves, 128x128 tile), XCD-chunked ->
//               fp32 partial traffic HALVED vs K-split 16.
//   K4 softmax: reduce 8 partials, softmax rows -> p (bf16)
//   K5 pv     : y = p . g; one block per (b, 64-d slice): g staged ONCE
//   K6 wconv  : w_y = y . w_w + w_b; 256 thr (4 waves, o-slice 64) -> 32
//               waves/CU; wy O-MAJOR per token + BN stats
//   K7 final  : pure streaming BN+residual (no LDS, no barriers)
// ---------------------------------------------------------------------------

typedef unsigned short u16t;
typedef short s16x8 __attribute__((ext_vector_type(8)));
typedef float f32x4 __attribute__((ext_vector_type(4)));
typedef uint32_t u32x4 __attribute__((ext_vector_type(4)));

#define DEV __device__ __forceinline__

DEV u16t f2bf(float f) {
    union { float f; uint32_t u; } v; v.f = f;
    return (u16t)((v.u + 0x7FFFu + ((v.u >> 16) & 1u)) >> 16);
}
DEV float bf2f(u16t h) {
    union { uint32_t u; float f; } v; v.u = ((uint32_t)h) << 16; return v.f;
}
DEV f32x4 MFMA(s16x8 a, s16x8 b, f32x4 c) {
    return __builtin_amdgcn_mfma_f32_16x16x32_bf16(a, b, c, 0, 0, 0);
}

// ---------------- K1: weight prep -> bf16 + stats zero -----------------------
__global__ void __launch_bounds__(256) k_prep(
    const float* __restrict__ gw, const float* __restrict__ tw,
    const float* __restrict__ pw, const float* __restrict__ ww,
    u16t* __restrict__ wb, float* __restrict__ stats)
{
    int i = blockIdx.x * 256 + threadIdx.x;
    if (blockIdx.x == 0) {
        stats[threadIdx.x] = 0.f;
        stats[256 + threadIdx.x] = 0.f;
    }
    if (i >= 32768) return;
    int o = i >> 8, c = i & 255;
    int fi = ((o >> 4) * 8 + (c >> 5)) * 512 + (((c >> 3) & 3) * 16 + (o & 15)) * 8 + (c & 7);
    float t = tw[i], p = pw[i];
    u16t th = f2bf(t); u16t tl = f2bf(t - bf2f(th));
    u16t ph = f2bf(p); u16t pl = f2bf(p - bf2f(ph));
    wb[fi] = th; wb[32768 + fi] = tl;
    wb[65536 + fi] = ph; wb[98304 + fi] = pl;
    wb[131072 + fi] = f2bf(gw[i]);
    wb[163840 + i] = f2bf(ww[i]);
}

// ---------------- K2: projections, 1 token/block, 8 waves, 64KB LDS ---------
__global__ void __launch_bounds__(512, 2) k_proj(
    const float* __restrict__ x, const u16t* __restrict__ wb,
    const float* __restrict__ tb, const float* __restrict__ pb, const float* __restrict__ gbias,
    float* __restrict__ out_t, float* __restrict__ out_p, u16t* __restrict__ out_g)
{
    __shared__ u16t xh[64 * 256];
    __shared__ u16t xl[64 * 256];
    int phys = blockIdx.x;
    int blk = ((phys & 7) << 8) | (phys >> 3);   // XCD chunking: one batch per XCD
    int b = blk >> 8, n = blk & 255;
    int pi = n >> 4, pj = n & 15;
    int t = threadIdx.x;
    int w = t >> 6, l = t & 63, lr = l & 15, lg = l >> 4;

    // ---- stage x hi/lo: lane = pixel, wave w covers octets [4w, 4w+4)
    {
        int p = l;
        const float* xb = x + (((size_t)b * 256) * 128 + pi * 8 + (p >> 3)) * 128 + pj * 8 + (p & 7);
        float v[4][8];
#pragma unroll
        for (int i = 0; i < 4; ++i)
#pragma unroll
            for (int j = 0; j < 8; ++j)
                v[i][j] = xb[(size_t)((w * 4 + i) * 8 + j) * 16384];
#pragma unroll
        for (int i = 0; i < 4; ++i) {
            int octet = w * 4 + i;
            u32x4 hv, lv;
#pragma unroll
            for (int j = 0; j < 8; j += 2) {
                uint32_t u0 = __float_as_uint(v[i][j]), u1 = __float_as_uint(v[i][j + 1]);
                hv[j >> 1] = (u0 >> 16) | (u1 & 0xFFFF0000u);          // truncation hi
                float f0 = v[i][j]     - __uint_as_float(u0 & 0xFFFF0000u);
                float f1 = v[i][j + 1] - __uint_as_float(u1 & 0xFFFF0000u);
                lv[j >> 1] = (uint32_t)f2bf(f0) | ((uint32_t)f2bf(f1) << 16);  // RN lo
            }
            int oct2 = (octet + p) & 31;
            *(s16x8*)(xh + p * 256 + oct2 * 8) = __builtin_bit_cast(s16x8, hv);
            *(s16x8*)(xl + p * 256 + oct2 * 8) = __builtin_bit_cast(s16x8, lv);
        }
    }
    __syncthreads();

    f32x4 aT[4], aP[4], aG[4];
#pragma unroll
    for (int ct = 0; ct < 4; ++ct) {
        aT[ct] = (f32x4){0.f, 0.f, 0.f, 0.f};
        aP[ct] = (f32x4){0.f, 0.f, 0.f, 0.f};
        aG[ct] = (f32x4){0.f, 0.f, 0.f, 0.f};
    }

#pragma unroll
    for (int kk = 0; kk < 8; ++kk) {
        size_t off = (size_t)((w * 8 + kk) * 64 + l) * 8;
        s16x8 th_ = *(const s16x8*)(wb + off);
        s16x8 tl_ = *(const s16x8*)(wb + 32768 + off);
        s16x8 ph_ = *(const s16x8*)(wb + 65536 + off);
        s16x8 pl_ = *(const s16x8*)(wb + 98304 + off);
        s16x8 gh_ = *(const s16x8*)(wb + 131072 + off);
#pragma unroll
        for (int ct = 0; ct < 4; ++ct) {
            int pr = ct * 16 + lr;
            int rot = (kk * 4 + lg + pr) & 31;
            s16x8 bh = *(const s16x8*)(xh + pr * 256 + rot * 8);
            s16x8 bl = *(const s16x8*)(xl + pr * 256 + rot * 8);
            aT[ct] = MFMA(th_, bh, aT[ct]);
            aT[ct] = MFMA(tl_, bh, aT[ct]);
            aT[ct] = MFMA(th_, bl, aT[ct]);
            aP[ct] = MFMA(ph_, bh, aP[ct]);
            aP[ct] = MFMA(pl_, bh, aP[ct]);
            aP[ct] = MFMA(ph_, bl, aP[ct]);
            aG[ct] = MFMA(gh_, bh, aG[ct]);
            aG[ct] = MFMA(gh_, bl, aG[ct]);
        }
    }

    // ---- epilogue
    size_t obase = ((size_t)b * 256 + n) * 8192;
#pragma unroll
    for (int r = 0; r < 4; ++r) {
        int o = w * 16 + lg * 4 + r;
        float bvT = tb[o], bvP = pb[o], bvG = gbias[o];
#pragma unroll
        for (int ct = 0; ct < 4; ++ct) {
            int s = ct * 16 + lr;
            size_t idx = obase + (size_t)o * 64 + s;
            out_t[idx] = aT[ct][r] + bvT;
            out_p[idx] = aP[ct][r] + bvP;
            out_g[idx] = f2bf(aG[ct][r] + bvG);
        }
    }
}

// ---------------- K3: QK^T, 3-term split, K-split 8 (BK=1024) ----------------
// grid 256 (XCD-chunked, 32/XCD), 512 thr = 8 waves: wave w -> rows (w&1)*64,
// cols (w>>1)*32 of the 128x128 tile. 32 kk iterations accumulate in regs.
__global__ void __launch_bounds__(512) k_qk(
    const float* __restrict__ th_g, const float* __restrict__ ph_g, float* __restrict__ fp)
{
    __shared__ u16t th[128 * 40], tl[128 * 40], ph[128 * 40], pl[128 * 40];
    int phys = blockIdx.x;
    int blk = ((phys & 7) << 5) | (phys >> 3);
    int mt = blk & 1, nt = (blk >> 1) & 1, b = (blk >> 2) & 7, kc = blk >> 5;  // kc 0..7
    int n0 = nt * 128, m0 = mt * 128;
    int t = threadIdx.x;
    int w = t >> 6, l = t & 63, lr = l & 15, lg = l >> 4;
    int wn = (w & 1) * 64, wm = (w >> 1) * 32;
    f32x4 acc[4][2];
#pragma unroll
    for (int i = 0; i < 4; ++i)
#pragma unroll
        for (int j = 0; j < 2; ++j) acc[i][j] = (f32x4){0.f, 0.f, 0.f, 0.f};

    const float* tsrc = th_g + ((size_t)b * 256 + n0) * 8192 + kc * 1024;
    const float* psrc = ph_g + ((size_t)b * 256 + m0) * 8192 + kc * 1024;

    for (int kk = 0; kk < 32; ++kk) {
        __syncthreads();
        // stage 256 rows (theta 0-127, phi 128-255) x 32 d, 16 threads... 512 thr
#pragma unroll
        for (int i = 0; i < 4; ++i) {
            int row = i * 64 + (t >> 3);
            int q = t & 7;
            int r7 = row & 127;
            const float* sp = ((row < 128) ? (tsrc + (size_t)r7 * 8192)
                                           : (psrc + (size_t)r7 * 8192)) + kk * 32 + q * 4;
            float4 v = *(const float4*)sp;
            u16t* dh = ((row < 128) ? th : ph) + r7 * 40 + q * 4;
            u16t* dl = ((row < 128) ? tl : pl) + r7 * 40 + q * 4;
            u16t h0 = f2bf(v.x), h1 = f2bf(v.y), h2 = f2bf(v.z), h3 = f2bf(v.w);
            *(ushort2*)dh       = make_ushort2(h0, h1);
            *(ushort2*)(dh + 2) = make_ushort2(h2, h3);
            *(ushort2*)dl       = make_ushort2(f2bf(v.x - bf2f(h0)), f2bf(v.y - bf2f(h1)));
            *(ushort2*)(dl + 2) = make_ushort2(f2bf(v.z - bf2f(h2)), f2bf(v.w - bf2f(h3)));
        }
        __syncthreads();
        s16x8 a_h[4], a_l[4], b_h[2], b_l[2];
#pragma unroll
        for (int rt = 0; rt < 4; ++rt) {
            int row = wn + rt * 16 + lr;
            a_h[rt] = *(const s16x8*)(th + row * 40 + lg * 8);
            a_l[rt] = *(const s16x8*)(tl + row * 40 + lg * 8);
        }
#pragma unroll
        for (int ct = 0; ct < 2; ++ct) {
            int row = wm + ct * 16 + lr;
            b_h[ct] = *(const s16x8*)(ph + row * 40 + lg * 8);
            b_l[ct] = *(const s16x8*)(pl + row * 40 + lg * 8);
        }
#pragma unroll
        for (int rt = 0; rt < 4; ++rt)
#pragma unroll
            for (int ct = 0; ct < 2; ++ct) {
                acc[rt][ct] = MFMA(a_h[rt], b_h[ct], acc[rt][ct]);
                acc[rt][ct] = MFMA(a_l[rt], b_h[ct], acc[rt][ct]);
                acc[rt][ct] = MFMA(a_h[rt], b_l[ct], acc[rt][ct]);
            }
    }
    float* dst = fp + (size_t)kc * 524288 + ((size_t)b * 256 + n0 + wn) * 256 + m0 + wm;
#pragma unroll
    for (int rt = 0; rt < 4; ++rt)
#pragma unroll
        for (int r = 0; r < 4; ++r) {
            int nn = rt * 16 + lg * 4 + r;
#pragma unroll
            for (int ct = 0; ct < 2; ++ct)
                dst[(size_t)nn * 256 + ct * 16 + lr] = acc[rt][ct][r];
        }
}

// ---------------- K4: reduce 8 partials + row softmax -> p bf16 --------------
__global__ void __launch_bounds__(256) k_softmax(
    const float* __restrict__ fp, u16t* __restrict__ pout)
{
    int row = blockIdx.x * 4 + (threadIdx.x >> 6);
    int l = threadIdx.x & 63;
    const float* src = fp + (size_t)row * 256 + l * 4;
    float4 s = {0.f, 0.f, 0.f, 0.f};
#pragma unroll
    for (int kc = 0; kc < 8; ++kc) {
        float4 v = *(const float4*)(src + (size_t)kc * 524288);
        s.x += v.x; s.y += v.y; s.z += v.z; s.w += v.w;
    }
    float mx = fmaxf(fmaxf(s.x, s.y), fmaxf(s.z, s.w));
#pragma unroll
    for (int d = 1; d < 64; d <<= 1) mx = fmaxf(mx, __shfl_xor(mx, d));
    float e0 = expf(s.x - mx), e1 = expf(s.y - mx), e2 = expf(s.z - mx), e3 = expf(s.w - mx);
    float sm = e0 + e1 + e2 + e3;
#pragma unroll
    for (int d = 1; d < 64; d <<= 1) sm += __shfl_xor(sm, d);
    float r = 1.f / sm;
    u16t* dst = pout + (size_t)row * 256 + l * 4;
    *(ushort4*)dst = make_ushort4(f2bf(e0 * r), f2bf(e1 * r), f2bf(e2 * r), f2bf(e3 * r));
}

// ---------------- K5: y = p . g  (one block per (b, 64-d slice)) -------------
__global__ void __launch_bounds__(512) k_pv(
    const u16t* __restrict__ pin, const u16t* __restrict__ g, u16t* __restrict__ y)
{
    __shared__ u16t gl[64 * 266];
    int phys = blockIdx.x;
    int blk = ((phys & 7) << 7) | (phys >> 3);   // one batch per XCD
    int b = blk >> 7, dt = blk & 127;
    int d0 = dt * 64;
    int t = threadIdx.x, w = t >> 6, l = t & 63, lr = l & 15, lg = l >> 4;
    int wn = w * 32;

    // ---- stage g once: thread = (m-pair, d-quarter); ushort2 writes
    {
        int mp = (t & 127) * 2;
        int dq = (t >> 7) * 16;
        const u16t* s0 = g + ((size_t)b * 256 + mp) * 8192 + d0 + dq;
        const u16t* s1 = s0 + 8192;
        s16x8 a0 = *(const s16x8*)s0;
        s16x8 a1 = *(const s16x8*)(s0 + 8);
        s16x8 b0 = *(const s16x8*)s1;
        s16x8 b1 = *(const s16x8*)(s1 + 8);
#pragma unroll
        for (int j = 0; j < 8; ++j) {
            *(ushort2*)(gl + (dq + j) * 266 + mp)     = make_ushort2((u16t)a0[j], (u16t)b0[j]);
            *(ushort2*)(gl + (dq + 8 + j) * 266 + mp) = make_ushort2((u16t)a1[j], (u16t)b1[j]);
        }
    }
    __syncthreads();

    f32x4 acc[2][4];
#pragma unroll
    for (int i = 0; i < 2; ++i)
#pragma unroll
        for (int j = 0; j < 4; ++j) acc[i][j] = (f32x4){0.f, 0.f, 0.f, 0.f};

#pragma unroll
    for (int mk = 0; mk < 8; ++mk) {
        s16x8 a[2];
#pragma unroll
        for (int rt = 0; rt < 2; ++rt)
            a[rt] = *(const s16x8*)(pin + ((size_t)b * 256 + wn + rt * 16 + lr) * 256
                                    + mk * 32 + lg * 8);
#pragma unroll
        for (int ct = 0; ct < 4; ++ct) {
            s16x8 bf = *(const s16x8*)(gl + (ct * 16 + lr) * 266 + mk * 32 + lg * 8);
#pragma unroll
            for (int rt = 0; rt < 2; ++rt)
                acc[rt][ct] = MFMA(a[rt], bf, acc[rt][ct]);
        }
    }
    u16t* yb = y + ((size_t)b * 256 + wn) * 8192 + d0;
#pragma unroll
    for (int rt = 0; rt < 2; ++rt)
#pragma unroll
        for (int r = 0; r < 4; ++r) {
            int nn = rt * 16 + lg * 4 + r;
#pragma unroll
            for (int ct = 0; ct < 4; ++ct)
                yb[(size_t)nn * 8192 + ct * 16 + lr] = f2bf(acc[rt][ct][r]);
        }
}

// ---------------- K6: w_y = y . w_w + w_b -> wy[b][n][o][s] + BN stats -------
// 256 thr = 4 waves; wave w owns o in [64w, 64w+64) (ct 0..3).
__global__ void __launch_bounds__(256) k_wconv(
    const u16t* __restrict__ y, const u16t* __restrict__ wb, const float* __restrict__ w_b,
    u16t* __restrict__ wy, float* __restrict__ stats)
{
    __shared__ u16t yl[64 * 40];
    int blk = blockIdx.x;
    int b = blk >> 8, n = blk & 255;
    int t = threadIdx.x, w = t >> 6, l = t & 63, lr = l & 15, lg = l >> 4;
    int wo = w * 64;
    const u16t* wcv = wb + 163840;
    const u16t* yb = y + ((size_t)b * 256 + n) * 8192;
    f32x4 acc[4][4];
#pragma unroll
    for (int i = 0; i < 4; ++i)
#pragma unroll
        for (int j = 0; j < 4; ++j) acc[i][j] = (f32x4){0.f, 0.f, 0.f, 0.f};

    for (int kk = 0; kk < 4; ++kk) {
        __syncthreads();
        {   // stage 32c x 64s -> yl[s][40] (transposed, scalar writes)
            const u16t* src = yb + kk * 2048 + t * 8;
            int c = t >> 3, s0 = (t & 7) * 8;
            s16x8 v0 = *(const s16x8*)src;
#pragma unroll
            for (int j = 0; j < 8; ++j)
                yl[(s0 + j) * 40 + c] = (u16t)v0[j];
        }
        __syncthreads();
        s16x8 a[4];
#pragma unroll
        for (int rt = 0; rt < 4; ++rt)
            a[rt] = *(const s16x8*)(yl + (rt * 16 + lr) * 40 + lg * 8);
#pragma unroll
        for (int ct = 0; ct < 4; ++ct) {
            int o = wo + ct * 16 + lr;
            s16x8 bf = *(const s16x8*)(wcv + o * 128 + kk * 32 + lg * 8);
#pragma unroll
            for (int rt = 0; rt < 4; ++rt)
                acc[rt][ct] = MFMA(a[rt], bf, acc[rt][ct]);
        }
    }
    // ---- epilogue: wy[b][n][o][s] (o-major token tile), ushort4 stores ------
    u16t* wyb = wy + ((size_t)b * 256 + n) * 16384;
    float s1[4], s2[4];
#pragma unroll
    for (int ct = 0; ct < 4; ++ct) { s1[ct] = 0.f; s2[ct] = 0.f; }
#pragma unroll
    for (int ct = 0; ct < 4; ++ct) {
        int o = wo + ct * 16 + lr;
        float bv = w_b[o];
#pragma unroll
        for (int rt = 0; rt < 4; ++rt) {
            float v0 = acc[rt][ct][0] + bv;
            float v1 = acc[rt][ct][1] + bv;
            float v2 = acc[rt][ct][2] + bv;
            float v3 = acc[rt][ct][3] + bv;
            s1[ct] += v0 + v1 + v2 + v3;
            s2[ct] += v0 * v0 + v1 * v1 + v2 * v2 + v3 * v3;
            *(ushort4*)(wyb + o * 64 + rt * 16 + lg * 4) =
                make_ushort4(f2bf(v0), f2bf(v1), f2bf(v2), f2bf(v3));
        }
    }
#pragma unroll
    for (int ct = 0; ct < 4; ++ct) {
        s1[ct] += __shfl_xor(s1[ct], 16); s1[ct] += __shfl_xor(s1[ct], 32);
        s2[ct] += __shfl_xor(s2[ct], 16); s2[ct] += __shfl_xor(s2[ct], 32);
        if (lg == 0) {
            int o = wo + ct * 16 + lr;
            atomicAdd(&stats[o], s1[ct]);
            atomicAdd(&stats[256 + o], s2[ct]);
        }
    }
}

// ---------------- K7: BN + residual, pure streaming (no LDS) -----------------
__global__ void __launch_bounds__(256) k_final(
    const u16t* __restrict__ wy, const float* __restrict__ x, const float* __restrict__ stats,
    const float* __restrict__ gamma, const float* __restrict__ beta, float* __restrict__ out)
{
    int blk = blockIdx.x;
    int ocg = blk & 15, pi = (blk >> 4) & 15, b = blk >> 8;
    int t = threadIdx.x;
    int pj = t & 15, ocs = t >> 4;
    int oc = ocg * 16 + ocs;
    int n = pi * 16 + pj;
    const float rcpN = 1.f / 131072.f;
    float mm = stats[oc] * rcpN;
    float vv = stats[256 + oc] * rcpN - mm * mm;
    float aa = gamma[oc] * rsqrtf(vv + 1e-5f);
    float cc = beta[oc] - mm * aa;
    const u16t* wyt = wy + (((size_t)b * 256 + n) * 256 + oc) * 64;
    size_t xbase = (((size_t)b * 256 + oc) * 128 + (size_t)pi * 8) * 128 + pj * 8;
#pragma unroll
    for (int u = 0; u < 8; ++u) {
        s16x8 v = *(const s16x8*)(wyt + u * 8);
        size_t xi = xbase + (size_t)u * 128;
        float4 x0 = *(const float4*)(x + xi);
        float4 x1 = *(const float4*)(x + xi + 4);
        float4 o0, o1;
        o0.x = bf2f((u16t)v[0]) * aa + cc + x0.x;
        o0.y = bf2f((u16t)v[1]) * aa + cc + x0.y;
        o0.z = bf2f((u16t)v[2]) * aa + cc + x0.z;
        o0.w = bf2f((u16t)v[3]) * aa + cc + x0.w;
        o1.x = bf2f((u16t)v[4]) * aa + cc + x1.x;
        o1.y = bf2f((u16t)v[5]) * aa + cc + x1.y;
        o1.z = bf2f((u16t)v[6]) * aa + cc + x1.z;
        o1.w = bf2f((u16t)v[7]) * aa + cc + x1.w;
        *(float4*)(out + xi) = o0;
        *(float4*)(out + xi + 4) = o1;
    }
}

// ---------------------------------------------------------------------------
extern "C" void kernel_launch(void* const* d_in, const int* in_sizes, int n_in,
                              void* d_out, int out_size, void* d_ws, size_t ws_size,
                              hipStream_t stream)
{
    (void)in_sizes; (void)n_in; (void)out_size;
    const float* x    = (const float*)d_in[0];
    const float* g_w  = (const float*)d_in[1];
    const float* g_b  = (const float*)d_in[2];
    const float* t_w  = (const float*)d_in[3];
    const float* t_b  = (const float*)d_in[4];
    const float* p_w  = (const float*)d_in[5];
    const float* p_b  = (const float*)d_in[6];
    const float* w_w  = (const float*)d_in[7];
    const float* w_b  = (const float*)d_in[8];
    const float* bn_g = (const float*)d_in[9];
    const float* bn_b = (const float*)d_in[10];

    const size_t G_OFF  = 0;
    const size_t FP_OFF = 33554432;
    const size_t WY_OFF = 33554432;          // aliases FP (dead after softmax)
    const size_t P_OFF  = 100663296;
    const size_t ST_OFF = 101711872;
    const size_t WB_OFF = 101713920;
    const size_t NEEDED = 102107136;
    if (ws_size < NEEDED) return;

    char* ws = (char*)d_ws;
    u16t*  g_buf = (u16t*)(ws + G_OFF);
    float* fp    = (float*)(ws + FP_OFF);
    u16t*  wy    = (u16t*)(ws + WY_OFF);
    u16t*  p_buf = (u16t*)(ws + P_OFF);
    float* stats = (float*)(ws + ST_OFF);
    u16t*  wb    = (u16t*)(ws + WB_OFF);

    float* th_g = (float*)d_out;             // theta fp32 (16.78M floats)
    float* ph_g = th_g + 16777216;           // phi fp32
    u16t*  y_buf = (u16t*)d_out;             // y bf16 (reuses d_out after QK)

    k_prep<<<128, 256, 0, stream>>>(g_w, t_w, p_w, w_w, wb, stats);
    k_proj<<<2048, 512, 0, stream>>>(x, wb, t_b, p_b, g_b, th_g, ph_g, g_buf);
    k_qk<<<256, 512, 0, stream>>>(th_g, ph_g, fp);
    k_softmax<<<512, 256, 0, stream>>>(fp, p_buf);
    k_pv<<<1024, 512, 0, stream>>>(p_buf, g_buf, y_buf);
    k_wconv<<<2048, 256, 0, stream>>>(y_buf, wb, w_b, wy, stats);
    k_final<<<2048, 256, 0, stream>>>(wy, x, stats, bn_g, bn_b, (float*)d_out);
}

// Round 18
// 323.960 us; speedup vs baseline: 1.0520x; 1.0520x over previous
//
#include <hip/hip_runtime.h>
#include <stdint.h>

// ---------------------------------------------------------------------------
// NonLocalBlockND: B=8, C_IN=256, C_INTER=128, H=W=128, P=16 -> tokens 256/batch,
// token dim D = 128*64 = 8192 (d = c*64 + s, s = u*8+v within 8x8 patch).
// Pipeline (best-measured combination of R16/R17 pieces):
//   K1 prep   : weights -> bf16 (A-fragment swizzled, hi/lo split) + zero stats
//   K2 proj   : ONE token/block, 512 thr (8 waves), 64KB LDS single-phase
//   K3 qk     : f = theta . phi (3-term split MFMA), K-split 16, 256 thr,
//               XCD-chunked (R16 shape - best measured)
//   K4 softmax: reduce 16 partials, softmax rows -> p (bf16)
//   K5 pv     : y = p . g; one block per (b, 64-d slice): g staged ONCE
//   K6 wconv  : w_y = y . w_w + w_b; 256 thr (4 waves, o-slice 64);
//               wy O-MAJOR per token + BN stats
//   K7 final  : pure streaming BN+residual (no LDS, no barriers)
// ---------------------------------------------------------------------------

typedef unsigned short u16t;
typedef short s16x8 __attribute__((ext_vector_type(8)));
typedef float f32x4 __attribute__((ext_vector_type(4)));
typedef uint32_t u32x4 __attribute__((ext_vector_type(4)));

#define DEV __device__ __forceinline__

DEV u16t f2bf(float f) {
    union { float f; uint32_t u; } v; v.f = f;
    return (u16t)((v.u + 0x7FFFu + ((v.u >> 16) & 1u)) >> 16);
}
DEV float bf2f(u16t h) {
    union { uint32_t u; float f; } v; v.u = ((uint32_t)h) << 16; return v.f;
}
DEV f32x4 MFMA(s16x8 a, s16x8 b, f32x4 c) {
    return __builtin_amdgcn_mfma_f32_16x16x32_bf16(a, b, c, 0, 0, 0);
}

// ---------------- K1: weight prep -> bf16 + stats zero -----------------------
__global__ void __launch_bounds__(256) k_prep(
    const float* __restrict__ gw, const float* __restrict__ tw,
    const float* __restrict__ pw, const float* __restrict__ ww,
    u16t* __restrict__ wb, float* __restrict__ stats)
{
    int i = blockIdx.x * 256 + threadIdx.x;
    if (blockIdx.x == 0) {
        stats[threadIdx.x] = 0.f;
        stats[256 + threadIdx.x] = 0.f;
    }
    if (i >= 32768) return;
    int o = i >> 8, c = i & 255;
    int fi = ((o >> 4) * 8 + (c >> 5)) * 512 + (((c >> 3) & 3) * 16 + (o & 15)) * 8 + (c & 7);
    float t = tw[i], p = pw[i];
    u16t th = f2bf(t); u16t tl = f2bf(t - bf2f(th));
    u16t ph = f2bf(p); u16t pl = f2bf(p - bf2f(ph));
    wb[fi] = th; wb[32768 + fi] = tl;
    wb[65536 + fi] = ph; wb[98304 + fi] = pl;
    wb[131072 + fi] = f2bf(gw[i]);
    wb[163840 + i] = f2bf(ww[i]);
}

// ---------------- K2: projections, 1 token/block, 8 waves, 64KB LDS ---------
__global__ void __launch_bounds__(512, 2) k_proj(
    const float* __restrict__ x, const u16t* __restrict__ wb,
    const float* __restrict__ tb, const float* __restrict__ pb, const float* __restrict__ gbias,
    float* __restrict__ out_t, float* __restrict__ out_p, u16t* __restrict__ out_g)
{
    __shared__ u16t xh[64 * 256];
    __shared__ u16t xl[64 * 256];
    int phys = blockIdx.x;
    int blk = ((phys & 7) << 8) | (phys >> 3);   // XCD chunking: one batch per XCD
    int b = blk >> 8, n = blk & 255;
    int pi = n >> 4, pj = n & 15;
    int t = threadIdx.x;
    int w = t >> 6, l = t & 63, lr = l & 15, lg = l >> 4;

    // ---- stage x hi/lo: lane = pixel, wave w covers octets [4w, 4w+4)
    {
        int p = l;
        const float* xb = x + (((size_t)b * 256) * 128 + pi * 8 + (p >> 3)) * 128 + pj * 8 + (p & 7);
        float v[4][8];
#pragma unroll
        for (int i = 0; i < 4; ++i)
#pragma unroll
            for (int j = 0; j < 8; ++j)
                v[i][j] = xb[(size_t)((w * 4 + i) * 8 + j) * 16384];
#pragma unroll
        for (int i = 0; i < 4; ++i) {
            int octet = w * 4 + i;
            u32x4 hv, lv;
#pragma unroll
            for (int j = 0; j < 8; j += 2) {
                uint32_t u0 = __float_as_uint(v[i][j]), u1 = __float_as_uint(v[i][j + 1]);
                hv[j >> 1] = (u0 >> 16) | (u1 & 0xFFFF0000u);          // truncation hi
                float f0 = v[i][j]     - __uint_as_float(u0 & 0xFFFF0000u);
                float f1 = v[i][j + 1] - __uint_as_float(u1 & 0xFFFF0000u);
                lv[j >> 1] = (uint32_t)f2bf(f0) | ((uint32_t)f2bf(f1) << 16);  // RN lo
            }
            int oct2 = (octet + p) & 31;
            *(s16x8*)(xh + p * 256 + oct2 * 8) = __builtin_bit_cast(s16x8, hv);
            *(s16x8*)(xl + p * 256 + oct2 * 8) = __builtin_bit_cast(s16x8, lv);
        }
    }
    __syncthreads();

    f32x4 aT[4], aP[4], aG[4];
#pragma unroll
    for (int ct = 0; ct < 4; ++ct) {
        aT[ct] = (f32x4){0.f, 0.f, 0.f, 0.f};
        aP[ct] = (f32x4){0.f, 0.f, 0.f, 0.f};
        aG[ct] = (f32x4){0.f, 0.f, 0.f, 0.f};
    }

#pragma unroll
    for (int kk = 0; kk < 8; ++kk) {
        size_t off = (size_t)((w * 8 + kk) * 64 + l) * 8;
        s16x8 th_ = *(const s16x8*)(wb + off);
        s16x8 tl_ = *(const s16x8*)(wb + 32768 + off);
        s16x8 ph_ = *(const s16x8*)(wb + 65536 + off);
        s16x8 pl_ = *(const s16x8*)(wb + 98304 + off);
        s16x8 gh_ = *(const s16x8*)(wb + 131072 + off);
#pragma unroll
        for (int ct = 0; ct < 4; ++ct) {
            int pr = ct * 16 + lr;
            int rot = (kk * 4 + lg + pr) & 31;
            s16x8 bh = *(const s16x8*)(xh + pr * 256 + rot * 8);
            s16x8 bl = *(const s16x8*)(xl + pr * 256 + rot * 8);
            aT[ct] = MFMA(th_, bh, aT[ct]);
            aT[ct] = MFMA(tl_, bh, aT[ct]);
            aT[ct] = MFMA(th_, bl, aT[ct]);
            aP[ct] = MFMA(ph_, bh, aP[ct]);
            aP[ct] = MFMA(pl_, bh, aP[ct]);
            aP[ct] = MFMA(ph_, bl, aP[ct]);
            aG[ct] = MFMA(gh_, bh, aG[ct]);
            aG[ct] = MFMA(gh_, bl, aG[ct]);
        }
    }

    // ---- epilogue
    size_t obase = ((size_t)b * 256 + n) * 8192;
#pragma unroll
    for (int r = 0; r < 4; ++r) {
        int o = w * 16 + lg * 4 + r;
        float bvT = tb[o], bvP = pb[o], bvG = gbias[o];
#pragma unroll
        for (int ct = 0; ct < 4; ++ct) {
            int s = ct * 16 + lr;
            size_t idx = obase + (size_t)o * 64 + s;
            out_t[idx] = aT[ct][r] + bvT;
            out_p[idx] = aP[ct][r] + bvP;
            out_g[idx] = f2bf(aG[ct][r] + bvG);
        }
    }
}

// ---------------- K3: QK^T, 3-term split, K-split 16 (R16 shape) -------------
__global__ void __launch_bounds__(256) k_qk(
    const float* __restrict__ th_g, const float* __restrict__ ph_g, float* __restrict__ fp)
{
    __shared__ u16t th[128 * 40], tl[128 * 40], ph[128 * 40], pl[128 * 40];
    int phys = blockIdx.x;
    int blk = ((phys & 7) << 6) | (phys >> 3);
    int mt = blk & 1, nt = (blk >> 1) & 1, b = (blk >> 2) & 7, kc = blk >> 5;
    int n0 = nt * 128, m0 = mt * 128;
    int t = threadIdx.x;
    int w = t >> 6, l = t & 63, lr = l & 15, lg = l >> 4;
    int wn = (w & 1) * 64, wm = (w >> 1) * 64;
    f32x4 acc[4][4];
#pragma unroll
    for (int i = 0; i < 4; ++i)
#pragma unroll
        for (int j = 0; j < 4; ++j) acc[i][j] = (f32x4){0.f, 0.f, 0.f, 0.f};

    const float* tsrc = th_g + ((size_t)b * 256 + n0) * 8192 + kc * 512;
    const float* psrc = ph_g + ((size_t)b * 256 + m0) * 8192 + kc * 512;

    for (int kk = 0; kk < 16; ++kk) {
        __syncthreads();
#pragma unroll
        for (int i = 0; i < 8; ++i) {
            int row = i * 32 + (t >> 3);
            int q = t & 7;
            int r7 = row & 127;
            const float* sp = ((row < 128) ? (tsrc + (size_t)r7 * 8192)
                                           : (psrc + (size_t)r7 * 8192)) + kk * 32 + q * 4;
            float4 v = *(const float4*)sp;
            u16t* dh = ((row < 128) ? th : ph) + r7 * 40 + q * 4;
            u16t* dl = ((row < 128) ? tl : pl) + r7 * 40 + q * 4;
            u16t h0 = f2bf(v.x), h1 = f2bf(v.y), h2 = f2bf(v.z), h3 = f2bf(v.w);
            *(ushort2*)dh       = make_ushort2(h0, h1);
            *(ushort2*)(dh + 2) = make_ushort2(h2, h3);
            *(ushort2*)dl       = make_ushort2(f2bf(v.x - bf2f(h0)), f2bf(v.y - bf2f(h1)));
            *(ushort2*)(dl + 2) = make_ushort2(f2bf(v.z - bf2f(h2)), f2bf(v.w - bf2f(h3)));
        }
        __syncthreads();
        s16x8 a_h[4], a_l[4], b_h[4], b_l[4];
#pragma unroll
        for (int rt = 0; rt < 4; ++rt) {
            int row = wn + rt * 16 + lr;
            a_h[rt] = *(const s16x8*)(th + row * 40 + lg * 8);
            a_l[rt] = *(const s16x8*)(tl + row * 40 + lg * 8);
        }
#pragma unroll
        for (int ct = 0; ct < 4; ++ct) {
            int row = wm + ct * 16 + lr;
            b_h[ct] = *(const s16x8*)(ph + row * 40 + lg * 8);
            b_l[ct] = *(const s16x8*)(pl + row * 40 + lg * 8);
        }
#pragma unroll
        for (int rt = 0; rt < 4; ++rt)
#pragma unroll
            for (int ct = 0; ct < 4; ++ct) {
                acc[rt][ct] = MFMA(a_h[rt], b_h[ct], acc[rt][ct]);
                acc[rt][ct] = MFMA(a_l[rt], b_h[ct], acc[rt][ct]);
                acc[rt][ct] = MFMA(a_h[rt], b_l[ct], acc[rt][ct]);
            }
    }
    float* dst = fp + (size_t)kc * 524288 + ((size_t)b * 256 + n0 + wn) * 256 + m0 + wm;
#pragma unroll
    for (int rt = 0; rt < 4; ++rt)
#pragma unroll
        for (int r = 0; r < 4; ++r) {
            int nn = rt * 16 + lg * 4 + r;
#pragma unroll
            for (int ct = 0; ct < 4; ++ct)
                dst[(size_t)nn * 256 + ct * 16 + lr] = acc[rt][ct][r];
        }
}

// ---------------- K4: reduce 16 partials + row softmax -> p bf16 -------------
__global__ void __launch_bounds__(256) k_softmax(
    const float* __restrict__ fp, u16t* __restrict__ pout)
{
    int row = blockIdx.x * 4 + (threadIdx.x >> 6);
    int l = threadIdx.x & 63;
    const float* src = fp + (size_t)row * 256 + l * 4;
    float4 s = {0.f, 0.f, 0.f, 0.f};
#pragma unroll
    for (int kc = 0; kc < 16; ++kc) {
        float4 v = *(const float4*)(src + (size_t)kc * 524288);
        s.x += v.x; s.y += v.y; s.z += v.z; s.w += v.w;
    }
    float mx = fmaxf(fmaxf(s.x, s.y), fmaxf(s.z, s.w));
#pragma unroll
    for (int d = 1; d < 64; d <<= 1) mx = fmaxf(mx, __shfl_xor(mx, d));
    float e0 = expf(s.x - mx), e1 = expf(s.y - mx), e2 = expf(s.z - mx), e3 = expf(s.w - mx);
    float sm = e0 + e1 + e2 + e3;
#pragma unroll
    for (int d = 1; d < 64; d <<= 1) sm += __shfl_xor(sm, d);
    float r = 1.f / sm;
    u16t* dst = pout + (size_t)row * 256 + l * 4;
    *(ushort4*)dst = make_ushort4(f2bf(e0 * r), f2bf(e1 * r), f2bf(e2 * r), f2bf(e3 * r));
}

// ---------------- K5: y = p . g  (one block per (b, 64-d slice)) -------------
__global__ void __launch_bounds__(512) k_pv(
    const u16t* __restrict__ pin, const u16t* __restrict__ g, u16t* __restrict__ y)
{
    __shared__ u16t gl[64 * 266];
    int phys = blockIdx.x;
    int blk = ((phys & 7) << 7) | (phys >> 3);   // one batch per XCD
    int b = blk >> 7, dt = blk & 127;
    int d0 = dt * 64;
    int t = threadIdx.x, w = t >> 6, l = t & 63, lr = l & 15, lg = l >> 4;
    int wn = w * 32;

    // ---- stage g once: thread = (m-pair, d-quarter); ushort2 writes
    {
        int mp = (t & 127) * 2;
        int dq = (t >> 7) * 16;
        const u16t* s0 = g + ((size_t)b * 256 + mp) * 8192 + d0 + dq;
        const u16t* s1 = s0 + 8192;
        s16x8 a0 = *(const s16x8*)s0;
        s16x8 a1 = *(const s16x8*)(s0 + 8);
        s16x8 b0 = *(const s16x8*)s1;
        s16x8 b1 = *(const s16x8*)(s1 + 8);
#pragma unroll
        for (int j = 0; j < 8; ++j) {
            *(ushort2*)(gl + (dq + j) * 266 + mp)     = make_ushort2((u16t)a0[j], (u16t)b0[j]);
            *(ushort2*)(gl + (dq + 8 + j) * 266 + mp) = make_ushort2((u16t)a1[j], (u16t)b1[j]);
        }
    }
    __syncthreads();

    f32x4 acc[2][4];
#pragma unroll
    for (int i = 0; i < 2; ++i)
#pragma unroll
        for (int j = 0; j < 4; ++j) acc[i][j] = (f32x4){0.f, 0.f, 0.f, 0.f};

#pragma unroll
    for (int mk = 0; mk < 8; ++mk) {
        s16x8 a[2];
#pragma unroll
        for (int rt = 0; rt < 2; ++rt)
            a[rt] = *(const s16x8*)(pin + ((size_t)b * 256 + wn + rt * 16 + lr) * 256
                                    + mk * 32 + lg * 8);
#pragma unroll
        for (int ct = 0; ct < 4; ++ct) {
            s16x8 bf = *(const s16x8*)(gl + (ct * 16 + lr) * 266 + mk * 32 + lg * 8);
#pragma unroll
            for (int rt = 0; rt < 2; ++rt)
                acc[rt][ct] = MFMA(a[rt], bf, acc[rt][ct]);
        }
    }
    u16t* yb = y + ((size_t)b * 256 + wn) * 8192 + d0;
#pragma unroll
    for (int rt = 0; rt < 2; ++rt)
#pragma unroll
        for (int r = 0; r < 4; ++r) {
            int nn = rt * 16 + lg * 4 + r;
#pragma unroll
            for (int ct = 0; ct < 4; ++ct)
                yb[(size_t)nn * 8192 + ct * 16 + lr] = f2bf(acc[rt][ct][r]);
        }
}

// ---------------- K6: w_y = y . w_w + w_b -> wy[b][n][o][s] + BN stats -------
// 256 thr = 4 waves; wave w owns o in [64w, 64w+64) (ct 0..3).
__global__ void __launch_bounds__(256) k_wconv(
    const u16t* __restrict__ y, const u16t* __restrict__ wb, const float* __restrict__ w_b,
    u16t* __restrict__ wy, float* __restrict__ stats)
{
    __shared__ u16t yl[64 * 40];
    int blk = blockIdx.x;
    int b = blk >> 8, n = blk & 255;
    int t = threadIdx.x, w = t >> 6, l = t & 63, lr = l & 15, lg = l >> 4;
    int wo = w * 64;
    const u16t* wcv = wb + 163840;
    const u16t* yb = y + ((size_t)b * 256 + n) * 8192;
    f32x4 acc[4][4];
#pragma unroll
    for (int i = 0; i < 4; ++i)
#pragma unroll
        for (int j = 0; j < 4; ++j) acc[i][j] = (f32x4){0.f, 0.f, 0.f, 0.f};

    for (int kk = 0; kk < 4; ++kk) {
        __syncthreads();
        {   // stage 32c x 64s -> yl[s][40] (transposed, scalar writes)
            const u16t* src = yb + kk * 2048 + t * 8;
            int c = t >> 3, s0 = (t & 7) * 8;
            s16x8 v0 = *(const s16x8*)src;
#pragma unroll
            for (int j = 0; j < 8; ++j)
                yl[(s0 + j) * 40 + c] = (u16t)v0[j];
        }
        __syncthreads();
        s16x8 a[4];
#pragma unroll
        for (int rt = 0; rt < 4; ++rt)
            a[rt] = *(const s16x8*)(yl + (rt * 16 + lr) * 40 + lg * 8);
#pragma unroll
        for (int ct = 0; ct < 4; ++ct) {
            int o = wo + ct * 16 + lr;
            s16x8 bf = *(const s16x8*)(wcv + o * 128 + kk * 32 + lg * 8);
#pragma unroll
            for (int rt = 0; rt < 4; ++rt)
                acc[rt][ct] = MFMA(a[rt], bf, acc[rt][ct]);
        }
    }
    // ---- epilogue: wy[b][n][o][s] (o-major token tile), ushort4 stores ------
    u16t* wyb = wy + ((size_t)b * 256 + n) * 16384;
    float s1[4], s2[4];
#pragma unroll
    for (int ct = 0; ct < 4; ++ct) { s1[ct] = 0.f; s2[ct] = 0.f; }
#pragma unroll
    for (int ct = 0; ct < 4; ++ct) {
        int o = wo + ct * 16 + lr;
        float bv = w_b[o];
#pragma unroll
        for (int rt = 0; rt < 4; ++rt) {
            float v0 = acc[rt][ct][0] + bv;
            float v1 = acc[rt][ct][1] + bv;
            float v2 = acc[rt][ct][2] + bv;
            float v3 = acc[rt][ct][3] + bv;
            s1[ct] += v0 + v1 + v2 + v3;
            s2[ct] += v0 * v0 + v1 * v1 + v2 * v2 + v3 * v3;
            *(ushort4*)(wyb + o * 64 + rt * 16 + lg * 4) =
                make_ushort4(f2bf(v0), f2bf(v1), f2bf(v2), f2bf(v3));
        }
    }
#pragma unroll
    for (int ct = 0; ct < 4; ++ct) {
        s1[ct] += __shfl_xor(s1[ct], 16); s1[ct] += __shfl_xor(s1[ct], 32);
        s2[ct] += __shfl_xor(s2[ct], 16); s2[ct] += __shfl_xor(s2[ct], 32);
        if (lg == 0) {
            int o = wo + ct * 16 + lr;
            atomicAdd(&stats[o], s1[ct]);
            atomicAdd(&stats[256 + o], s2[ct]);
        }
    }
}

// ---------------- K7: BN + residual, pure streaming (no LDS) -----------------
__global__ void __launch_bounds__(256) k_final(
    const u16t* __restrict__ wy, const float* __restrict__ x, const float* __restrict__ stats,
    const float* __restrict__ gamma, const float* __restrict__ beta, float* __restrict__ out)
{
    int blk = blockIdx.x;
    int ocg = blk & 15, pi = (blk >> 4) & 15, b = blk >> 8;
    int t = threadIdx.x;
    int pj = t & 15, ocs = t >> 4;
    int oc = ocg * 16 + ocs;
    int n = pi * 16 + pj;
    const float rcpN = 1.f / 131072.f;
    float mm = stats[oc] * rcpN;
    float vv = stats[256 + oc] * rcpN - mm * mm;
    float aa = gamma[oc] * rsqrtf(vv + 1e-5f);
    float cc = beta[oc] - mm * aa;
    const u16t* wyt = wy + (((size_t)b * 256 + n) * 256 + oc) * 64;
    size_t xbase = (((size_t)b * 256 + oc) * 128 + (size_t)pi * 8) * 128 + pj * 8;
#pragma unroll
    for (int u = 0; u < 8; ++u) {
        s16x8 v = *(const s16x8*)(wyt + u * 8);
        size_t xi = xbase + (size_t)u * 128;
        float4 x0 = *(const float4*)(x + xi);
        float4 x1 = *(const float4*)(x + xi + 4);
        float4 o0, o1;
        o0.x = bf2f((u16t)v[0]) * aa + cc + x0.x;
        o0.y = bf2f((u16t)v[1]) * aa + cc + x0.y;
        o0.z = bf2f((u16t)v[2]) * aa + cc + x0.z;
        o0.w = bf2f((u16t)v[3]) * aa + cc + x0.w;
        o1.x = bf2f((u16t)v[4]) * aa + cc + x1.x;
        o1.y = bf2f((u16t)v[5]) * aa + cc + x1.y;
        o1.z = bf2f((u16t)v[6]) * aa + cc + x1.z;
        o1.w = bf2f((u16t)v[7]) * aa + cc + x1.w;
        *(float4*)(out + xi) = o0;
        *(float4*)(out + xi + 4) = o1;
    }
}

// ---------------------------------------------------------------------------
extern "C" void kernel_launch(void* const* d_in, const int* in_sizes, int n_in,
                              void* d_out, int out_size, void* d_ws, size_t ws_size,
                              hipStream_t stream)
{
    (void)in_sizes; (void)n_in; (void)out_size;
    const float* x    = (const float*)d_in[0];
    const float* g_w  = (const float*)d_in[1];
    const float* g_b  = (const float*)d_in[2];
    const float* t_w  = (const float*)d_in[3];
    const float* t_b  = (const float*)d_in[4];
    const float* p_w  = (const float*)d_in[5];
    const float* p_b  = (const float*)d_in[6];
    const float* w_w  = (const float*)d_in[7];
    const float* w_b  = (const float*)d_in[8];
    const float* bn_g = (const float*)d_in[9];
    const float* bn_b = (const float*)d_in[10];

    const size_t G_OFF  = 0;
    const size_t FP_OFF = 33554432;
    const size_t WY_OFF = 33554432;          // aliases FP (dead after softmax)
    const size_t P_OFF  = 100663296;
    const size_t ST_OFF = 101711872;
    const size_t WB_OFF = 101713920;
    const size_t NEEDED = 102107136;
    if (ws_size < NEEDED) return;

    char* ws = (char*)d_ws;
    u16t*  g_buf = (u16t*)(ws + G_OFF);
    float* fp    = (float*)(ws + FP_OFF);
    u16t*  wy    = (u16t*)(ws + WY_OFF);
    u16t*  p_buf = (u16t*)(ws + P_OFF);
    float* stats = (float*)(ws + ST_OFF);
    u16t*  wb    = (u16t*)(ws + WB_OFF);

    float* th_g = (float*)d_out;             // theta fp32 (16.78M floats)
    float* ph_g = th_g + 16777216;           // phi fp32
    u16t*  y_buf = (u16t*)d_out;             // y bf16 (reuses d_out after QK)

    k_prep<<<128, 256, 0, stream>>>(g_w, t_w, p_w, w_w, wb, stats);
    k_proj<<<2048, 512, 0, stream>>>(x, wb, t_b, p_b, g_b, th_g, ph_g, g_buf);
    k_qk<<<512, 256, 0, stream>>>(th_g, ph_g, fp);
    k_softmax<<<512, 256, 0, stream>>>(fp, p_buf);
    k_pv<<<1024, 512, 0, stream>>>(p_buf, g_buf, y_buf);
    k_wconv<<<2048, 256, 0, stream>>>(y_buf, wb, w_b, wy, stats);
    k_final<<<2048, 256, 0, stream>>>(wy, x, stats, bn_g, bn_b, (float*)d_out);
}

// Round 19
// 322.946 us; speedup vs baseline: 1.0553x; 1.0031x over previous
//
#include <hip/hip_runtime.h>
#include <stdint.h>

// ---------------------------------------------------------------------------
// NonLocalBlockND: B=8, C_IN=256, C_INTER=128, H=W=128, P=16 -> tokens 256/batch,
// token dim D = 128*64 = 8192 (d = c*64 + s, s = u*8+v within 8x8 patch).
// Pipeline (R18 base; k_proj g-projection trimmed to 1-term x (hi only)):
//   K1 prep   : weights -> bf16 (A-fragment swizzled, hi/lo split) + zero stats
//   K2 proj   : ONE token/block, 512 thr (8 waves), 64KB LDS single-phase;
//               theta/phi 3-term split MFMA, g 1-term (W_hi x_hi) -- error
//               ~0.002 (linear path, no D-amplification), 7 MFMA/(kk,ct).
//   K3 qk     : f = theta . phi (3-term split MFMA), K-split 16, 256 thr
//   K4 softmax: reduce 16 partials, softmax rows -> p (bf16)
//   K5 pv     : y = p . g; one block per (b, 64-d slice): g staged ONCE
//   K6 wconv  : w_y = y . w_w + w_b; 256 thr (4 waves); wy O-MAJOR + BN stats
//   K7 final  : pure streaming BN+residual (no LDS, no barriers)
// ---------------------------------------------------------------------------

typedef unsigned short u16t;
typedef short s16x8 __attribute__((ext_vector_type(8)));
typedef float f32x4 __attribute__((ext_vector_type(4)));
typedef uint32_t u32x4 __attribute__((ext_vector_type(4)));

#define DEV __device__ __forceinline__

DEV u16t f2bf(float f) {
    union { float f; uint32_t u; } v; v.f = f;
    return (u16t)((v.u + 0x7FFFu + ((v.u >> 16) & 1u)) >> 16);
}
DEV float bf2f(u16t h) {
    union { uint32_t u; float f; } v; v.u = ((uint32_t)h) << 16; return v.f;
}
DEV f32x4 MFMA(s16x8 a, s16x8 b, f32x4 c) {
    return __builtin_amdgcn_mfma_f32_16x16x32_bf16(a, b, c, 0, 0, 0);
}

// ---------------- K1: weight prep -> bf16 + stats zero -----------------------
__global__ void __launch_bounds__(256) k_prep(
    const float* __restrict__ gw, const float* __restrict__ tw,
    const float* __restrict__ pw, const float* __restrict__ ww,
    u16t* __restrict__ wb, float* __restrict__ stats)
{
    int i = blockIdx.x * 256 + threadIdx.x;
    if (blockIdx.x == 0) {
        stats[threadIdx.x] = 0.f;
        stats[256 + threadIdx.x] = 0.f;
    }
    if (i >= 32768) return;
    int o = i >> 8, c = i & 255;
    int fi = ((o >> 4) * 8 + (c >> 5)) * 512 + (((c >> 3) & 3) * 16 + (o & 15)) * 8 + (c & 7);
    float t = tw[i], p = pw[i];
    u16t th = f2bf(t); u16t tl = f2bf(t - bf2f(th));
    u16t ph = f2bf(p); u16t pl = f2bf(p - bf2f(ph));
    wb[fi] = th; wb[32768 + fi] = tl;
    wb[65536 + fi] = ph; wb[98304 + fi] = pl;
    wb[131072 + fi] = f2bf(gw[i]);
    wb[163840 + i] = f2bf(ww[i]);
}

// ---------------- K2: projections, 1 token/block, 8 waves, 64KB LDS ---------
__global__ void __launch_bounds__(512, 2) k_proj(
    const float* __restrict__ x, const u16t* __restrict__ wb,
    const float* __restrict__ tb, const float* __restrict__ pb, const float* __restrict__ gbias,
    float* __restrict__ out_t, float* __restrict__ out_p, u16t* __restrict__ out_g)
{
    __shared__ u16t xh[64 * 256];
    __shared__ u16t xl[64 * 256];
    int phys = blockIdx.x;
    int blk = ((phys & 7) << 8) | (phys >> 3);   // XCD chunking: one batch per XCD
    int b = blk >> 8, n = blk & 255;
    int pi = n >> 4, pj = n & 15;
    int t = threadIdx.x;
    int w = t >> 6, l = t & 63, lr = l & 15, lg = l >> 4;

    // ---- stage x hi/lo: lane = pixel, wave w covers octets [4w, 4w+4)
    {
        int p = l;
        const float* xb = x + (((size_t)b * 256) * 128 + pi * 8 + (p >> 3)) * 128 + pj * 8 + (p & 7);
        float v[4][8];
#pragma unroll
        for (int i = 0; i < 4; ++i)
#pragma unroll
            for (int j = 0; j < 8; ++j)
                v[i][j] = xb[(size_t)((w * 4 + i) * 8 + j) * 16384];
#pragma unroll
        for (int i = 0; i < 4; ++i) {
            int octet = w * 4 + i;
            u32x4 hv, lv;
#pragma unroll
            for (int j = 0; j < 8; j += 2) {
                uint32_t u0 = __float_as_uint(v[i][j]), u1 = __float_as_uint(v[i][j + 1]);
                hv[j >> 1] = (u0 >> 16) | (u1 & 0xFFFF0000u);          // truncation hi
                float f0 = v[i][j]     - __uint_as_float(u0 & 0xFFFF0000u);
                float f1 = v[i][j + 1] - __uint_as_float(u1 & 0xFFFF0000u);
                lv[j >> 1] = (uint32_t)f2bf(f0) | ((uint32_t)f2bf(f1) << 16);  // RN lo
            }
            int oct2 = (octet + p) & 31;
            *(s16x8*)(xh + p * 256 + oct2 * 8) = __builtin_bit_cast(s16x8, hv);
            *(s16x8*)(xl + p * 256 + oct2 * 8) = __builtin_bit_cast(s16x8, lv);
        }
    }
    __syncthreads();

    f32x4 aT[4], aP[4], aG[4];
#pragma unroll
    for (int ct = 0; ct < 4; ++ct) {
        aT[ct] = (f32x4){0.f, 0.f, 0.f, 0.f};
        aP[ct] = (f32x4){0.f, 0.f, 0.f, 0.f};
        aG[ct] = (f32x4){0.f, 0.f, 0.f, 0.f};
    }

#pragma unroll
    for (int kk = 0; kk < 8; ++kk) {
        size_t off = (size_t)((w * 8 + kk) * 64 + l) * 8;
        s16x8 th_ = *(const s16x8*)(wb + off);
        s16x8 tl_ = *(const s16x8*)(wb + 32768 + off);
        s16x8 ph_ = *(const s16x8*)(wb + 65536 + off);
        s16x8 pl_ = *(const s16x8*)(wb + 98304 + off);
        s16x8 gh_ = *(const s16x8*)(wb + 131072 + off);
#pragma unroll
        for (int ct = 0; ct < 4; ++ct) {
            int pr = ct * 16 + lr;
            int rot = (kk * 4 + lg + pr) & 31;
            s16x8 bh = *(const s16x8*)(xh + pr * 256 + rot * 8);
            s16x8 bl = *(const s16x8*)(xl + pr * 256 + rot * 8);
            aT[ct] = MFMA(th_, bh, aT[ct]);
            aT[ct] = MFMA(tl_, bh, aT[ct]);
            aT[ct] = MFMA(th_, bl, aT[ct]);
            aP[ct] = MFMA(ph_, bh, aP[ct]);
            aP[ct] = MFMA(pl_, bh, aP[ct]);
            aP[ct] = MFMA(ph_, bl, aP[ct]);
            aG[ct] = MFMA(gh_, bh, aG[ct]);   // g: 1-term (hi only)
        }
    }

    // ---- epilogue
    size_t obase = ((size_t)b * 256 + n) * 8192;
#pragma unroll
    for (int r = 0; r < 4; ++r) {
        int o = w * 16 + lg * 4 + r;
        float bvT = tb[o], bvP = pb[o], bvG = gbias[o];
#pragma unroll
        for (int ct = 0; ct < 4; ++ct) {
            int s = ct * 16 + lr;
            size_t idx = obase + (size_t)o * 64 + s;
            out_t[idx] = aT[ct][r] + bvT;
            out_p[idx] = aP[ct][r] + bvP;
            out_g[idx] = f2bf(aG[ct][r] + bvG);
        }
    }
}

// ---------------- K3: QK^T, 3-term split, K-split 16 (R16 shape) -------------
__global__ void __launch_bounds__(256) k_qk(
    const float* __restrict__ th_g, const float* __restrict__ ph_g, float* __restrict__ fp)
{
    __shared__ u16t th[128 * 40], tl[128 * 40], ph[128 * 40], pl[128 * 40];
    int phys = blockIdx.x;
    int blk = ((phys & 7) << 6) | (phys >> 3);
    int mt = blk & 1, nt = (blk >> 1) & 1, b = (blk >> 2) & 7, kc = blk >> 5;
    int n0 = nt * 128, m0 = mt * 128;
    int t = threadIdx.x;
    int w = t >> 6, l = t & 63, lr = l & 15, lg = l >> 4;
    int wn = (w & 1) * 64, wm = (w >> 1) * 64;
    f32x4 acc[4][4];
#pragma unroll
    for (int i = 0; i < 4; ++i)
#pragma unroll
        for (int j = 0; j < 4; ++j) acc[i][j] = (f32x4){0.f, 0.f, 0.f, 0.f};

    const float* tsrc = th_g + ((size_t)b * 256 + n0) * 8192 + kc * 512;
    const float* psrc = ph_g + ((size_t)b * 256 + m0) * 8192 + kc * 512;

    for (int kk = 0; kk < 16; ++kk) {
        __syncthreads();
#pragma unroll
        for (int i = 0; i < 8; ++i) {
            int row = i * 32 + (t >> 3);
            int q = t & 7;
            int r7 = row & 127;
            const float* sp = ((row < 128) ? (tsrc + (size_t)r7 * 8192)
                                           : (psrc + (size_t)r7 * 8192)) + kk * 32 + q * 4;
            float4 v = *(const float4*)sp;
            u16t* dh = ((row < 128) ? th : ph) + r7 * 40 + q * 4;
            u16t* dl = ((row < 128) ? tl : pl) + r7 * 40 + q * 4;
            u16t h0 = f2bf(v.x), h1 = f2bf(v.y), h2 = f2bf(v.z), h3 = f2bf(v.w);
            *(ushort2*)dh       = make_ushort2(h0, h1);
            *(ushort2*)(dh + 2) = make_ushort2(h2, h3);
            *(ushort2*)dl       = make_ushort2(f2bf(v.x - bf2f(h0)), f2bf(v.y - bf2f(h1)));
            *(ushort2*)(dl + 2) = make_ushort2(f2bf(v.z - bf2f(h2)), f2bf(v.w - bf2f(h3)));
        }
        __syncthreads();
        s16x8 a_h[4], a_l[4], b_h[4], b_l[4];
#pragma unroll
        for (int rt = 0; rt < 4; ++rt) {
            int row = wn + rt * 16 + lr;
            a_h[rt] = *(const s16x8*)(th + row * 40 + lg * 8);
            a_l[rt] = *(const s16x8*)(tl + row * 40 + lg * 8);
        }
#pragma unroll
        for (int ct = 0; ct < 4; ++ct) {
            int row = wm + ct * 16 + lr;
            b_h[ct] = *(const s16x8*)(ph + row * 40 + lg * 8);
            b_l[ct] = *(const s16x8*)(pl + row * 40 + lg * 8);
        }
#pragma unroll
        for (int rt = 0; rt < 4; ++rt)
#pragma unroll
            for (int ct = 0; ct < 4; ++ct) {
                acc[rt][ct] = MFMA(a_h[rt], b_h[ct], acc[rt][ct]);
                acc[rt][ct] = MFMA(a_l[rt], b_h[ct], acc[rt][ct]);
                acc[rt][ct] = MFMA(a_h[rt], b_l[ct], acc[rt][ct]);
            }
    }
    float* dst = fp + (size_t)kc * 524288 + ((size_t)b * 256 + n0 + wn) * 256 + m0 + wm;
#pragma unroll
    for (int rt = 0; rt < 4; ++rt)
#pragma unroll
        for (int r = 0; r < 4; ++r) {
            int nn = rt * 16 + lg * 4 + r;
#pragma unroll
            for (int ct = 0; ct < 4; ++ct)
                dst[(size_t)nn * 256 + ct * 16 + lr] = acc[rt][ct][r];
        }
}

// ---------------- K4: reduce 16 partials + row softmax -> p bf16 -------------
__global__ void __launch_bounds__(256) k_softmax(
    const float* __restrict__ fp, u16t* __restrict__ pout)
{
    int row = blockIdx.x * 4 + (threadIdx.x >> 6);
    int l = threadIdx.x & 63;
    const float* src = fp + (size_t)row * 256 + l * 4;
    float4 s = {0.f, 0.f, 0.f, 0.f};
#pragma unroll
    for (int kc = 0; kc < 16; ++kc) {
        float4 v = *(const float4*)(src + (size_t)kc * 524288);
        s.x += v.x; s.y += v.y; s.z += v.z; s.w += v.w;
    }
    float mx = fmaxf(fmaxf(s.x, s.y), fmaxf(s.z, s.w));
#pragma unroll
    for (int d = 1; d < 64; d <<= 1) mx = fmaxf(mx, __shfl_xor(mx, d));
    float e0 = expf(s.x - mx), e1 = expf(s.y - mx), e2 = expf(s.z - mx), e3 = expf(s.w - mx);
    float sm = e0 + e1 + e2 + e3;
#pragma unroll
    for (int d = 1; d < 64; d <<= 1) sm += __shfl_xor(sm, d);
    float r = 1.f / sm;
    u16t* dst = pout + (size_t)row * 256 + l * 4;
    *(ushort4*)dst = make_ushort4(f2bf(e0 * r), f2bf(e1 * r), f2bf(e2 * r), f2bf(e3 * r));
}

// ---------------- K5: y = p . g  (one block per (b, 64-d slice)) -------------
__global__ void __launch_bounds__(512) k_pv(
    const u16t* __restrict__ pin, const u16t* __restrict__ g, u16t* __restrict__ y)
{
    __shared__ u16t gl[64 * 266];
    int phys = blockIdx.x;
    int blk = ((phys & 7) << 7) | (phys >> 3);   // one batch per XCD
    int b = blk >> 7, dt = blk & 127;
    int d0 = dt * 64;
    int t = threadIdx.x, w = t >> 6, l = t & 63, lr = l & 15, lg = l >> 4;
    int wn = w * 32;

    // ---- stage g once: thread = (m-pair, d-quarter); ushort2 writes
    {
        int mp = (t & 127) * 2;
        int dq = (t >> 7) * 16;
        const u16t* s0 = g + ((size_t)b * 256 + mp) * 8192 + d0 + dq;
        const u16t* s1 = s0 + 8192;
        s16x8 a0 = *(const s16x8*)s0;
        s16x8 a1 = *(const s16x8*)(s0 + 8);
        s16x8 b0 = *(const s16x8*)s1;
        s16x8 b1 = *(const s16x8*)(s1 + 8);
#pragma unroll
        for (int j = 0; j < 8; ++j) {
            *(ushort2*)(gl + (dq + j) * 266 + mp)     = make_ushort2((u16t)a0[j], (u16t)b0[j]);
            *(ushort2*)(gl + (dq + 8 + j) * 266 + mp) = make_ushort2((u16t)a1[j], (u16t)b1[j]);
        }
    }
    __syncthreads();

    f32x4 acc[2][4];
#pragma unroll
    for (int i = 0; i < 2; ++i)
#pragma unroll
        for (int j = 0; j < 4; ++j) acc[i][j] = (f32x4){0.f, 0.f, 0.f, 0.f};

#pragma unroll
    for (int mk = 0; mk < 8; ++mk) {
        s16x8 a[2];
#pragma unroll
        for (int rt = 0; rt < 2; ++rt)
            a[rt] = *(const s16x8*)(pin + ((size_t)b * 256 + wn + rt * 16 + lr) * 256
                                    + mk * 32 + lg * 8);
#pragma unroll
        for (int ct = 0; ct < 4; ++ct) {
            s16x8 bf = *(const s16x8*)(gl + (ct * 16 + lr) * 266 + mk * 32 + lg * 8);
#pragma unroll
            for (int rt = 0; rt < 2; ++rt)
                acc[rt][ct] = MFMA(a[rt], bf, acc[rt][ct]);
        }
    }
    u16t* yb = y + ((size_t)b * 256 + wn) * 8192 + d0;
#pragma unroll
    for (int rt = 0; rt < 2; ++rt)
#pragma unroll
        for (int r = 0; r < 4; ++r) {
            int nn = rt * 16 + lg * 4 + r;
#pragma unroll
            for (int ct = 0; ct < 4; ++ct)
                yb[(size_t)nn * 8192 + ct * 16 + lr] = f2bf(acc[rt][ct][r]);
        }
}

// ---------------- K6: w_y = y . w_w + w_b -> wy[b][n][o][s] + BN stats -------
// 256 thr = 4 waves; wave w owns o in [64w, 64w+64) (ct 0..3).
__global__ void __launch_bounds__(256) k_wconv(
    const u16t* __restrict__ y, const u16t* __restrict__ wb, const float* __restrict__ w_b,
    u16t* __restrict__ wy, float* __restrict__ stats)
{
    __shared__ u16t yl[64 * 40];
    int blk = blockIdx.x;
    int b = blk >> 8, n = blk & 255;
    int t = threadIdx.x, w = t >> 6, l = t & 63, lr = l & 15, lg = l >> 4;
    int wo = w * 64;
    const u16t* wcv = wb + 163840;
    const u16t* yb = y + ((size_t)b * 256 + n) * 8192;
    f32x4 acc[4][4];
#pragma unroll
    for (int i = 0; i < 4; ++i)
#pragma unroll
        for (int j = 0; j < 4; ++j) acc[i][j] = (f32x4){0.f, 0.f, 0.f, 0.f};

    for (int kk = 0; kk < 4; ++kk) {
        __syncthreads();
        {   // stage 32c x 64s -> yl[s][40] (transposed, scalar writes)
            const u16t* src = yb + kk * 2048 + t * 8;
            int c = t >> 3, s0 = (t & 7) * 8;
            s16x8 v0 = *(const s16x8*)src;
#pragma unroll
            for (int j = 0; j < 8; ++j)
                yl[(s0 + j) * 40 + c] = (u16t)v0[j];
        }
        __syncthreads();
        s16x8 a[4];
#pragma unroll
        for (int rt = 0; rt < 4; ++rt)
            a[rt] = *(const s16x8*)(yl + (rt * 16 + lr) * 40 + lg * 8);
#pragma unroll
        for (int ct = 0; ct < 4; ++ct) {
            int o = wo + ct * 16 + lr;
            s16x8 bf = *(const s16x8*)(wcv + o * 128 + kk * 32 + lg * 8);
#pragma unroll
            for (int rt = 0; rt < 4; ++rt)
                acc[rt][ct] = MFMA(a[rt], bf, acc[rt][ct]);
        }
    }
    // ---- epilogue: wy[b][n][o][s] (o-major token tile), ushort4 stores ------
    u16t* wyb = wy + ((size_t)b * 256 + n) * 16384;
    float s1[4], s2[4];
#pragma unroll
    for (int ct = 0; ct < 4; ++ct) { s1[ct] = 0.f; s2[ct] = 0.f; }
#pragma unroll
    for (int ct = 0; ct < 4; ++ct) {
        int o = wo + ct * 16 + lr;
        float bv = w_b[o];
#pragma unroll
        for (int rt = 0; rt < 4; ++rt) {
            float v0 = acc[rt][ct][0] + bv;
            float v1 = acc[rt][ct][1] + bv;
            float v2 = acc[rt][ct][2] + bv;
            float v3 = acc[rt][ct][3] + bv;
            s1[ct] += v0 + v1 + v2 + v3;
            s2[ct] += v0 * v0 + v1 * v1 + v2 * v2 + v3 * v3;
            *(ushort4*)(wyb + o * 64 + rt * 16 + lg * 4) =
                make_ushort4(f2bf(v0), f2bf(v1), f2bf(v2), f2bf(v3));
        }
    }
#pragma unroll
    for (int ct = 0; ct < 4; ++ct) {
        s1[ct] += __shfl_xor(s1[ct], 16); s1[ct] += __shfl_xor(s1[ct], 32);
        s2[ct] += __shfl_xor(s2[ct], 16); s2[ct] += __shfl_xor(s2[ct], 32);
        if (lg == 0) {
            int o = wo + ct * 16 + lr;
            atomicAdd(&stats[o], s1[ct]);
            atomicAdd(&stats[256 + o], s2[ct]);
        }
    }
}

// ---------------- K7: BN + residual, pure streaming (no LDS) -----------------
__global__ void __launch_bounds__(256) k_final(
    const u16t* __restrict__ wy, const float* __restrict__ x, const float* __restrict__ stats,
    const float* __restrict__ gamma, const float* __restrict__ beta, float* __restrict__ out)
{
    int blk = blockIdx.x;
    int ocg = blk & 15, pi = (blk >> 4) & 15, b = blk >> 8;
    int t = threadIdx.x;
    int pj = t & 15, ocs = t >> 4;
    int oc = ocg * 16 + ocs;
    int n = pi * 16 + pj;
    const float rcpN = 1.f / 131072.f;
    float mm = stats[oc] * rcpN;
    float vv = stats[256 + oc] * rcpN - mm * mm;
    float aa = gamma[oc] * rsqrtf(vv + 1e-5f);
    float cc = beta[oc] - mm * aa;
    const u16t* wyt = wy + (((size_t)b * 256 + n) * 256 + oc) * 64;
    size_t xbase = (((size_t)b * 256 + oc) * 128 + (size_t)pi * 8) * 128 + pj * 8;
#pragma unroll
    for (int u = 0; u < 8; ++u) {
        s16x8 v = *(const s16x8*)(wyt + u * 8);
        size_t xi = xbase + (size_t)u * 128;
        float4 x0 = *(const float4*)(x + xi);
        float4 x1 = *(const float4*)(x + xi + 4);
        float4 o0, o1;
        o0.x = bf2f((u16t)v[0]) * aa + cc + x0.x;
        o0.y = bf2f((u16t)v[1]) * aa + cc + x0.y;
        o0.z = bf2f((u16t)v[2]) * aa + cc + x0.z;
        o0.w = bf2f((u16t)v[3]) * aa + cc + x0.w;
        o1.x = bf2f((u16t)v[4]) * aa + cc + x1.x;
        o1.y = bf2f((u16t)v[5]) * aa + cc + x1.y;
        o1.z = bf2f((u16t)v[6]) * aa + cc + x1.z;
        o1.w = bf2f((u16t)v[7]) * aa + cc + x1.w;
        *(float4*)(out + xi) = o0;
        *(float4*)(out + xi + 4) = o1;
    }
}

// ---------------------------------------------------------------------------
extern "C" void kernel_launch(void* const* d_in, const int* in_sizes, int n_in,
                              void* d_out, int out_size, void* d_ws, size_t ws_size,
                              hipStream_t stream)
{
    (void)in_sizes; (void)n_in; (void)out_size;
    const float* x    = (const float*)d_in[0];
    const float* g_w  = (const float*)d_in[1];
    const float* g_b  = (const float*)d_in[2];
    const float* t_w  = (const float*)d_in[3];
    const float* t_b  = (const float*)d_in[4];
    const float* p_w  = (const float*)d_in[5];
    const float* p_b  = (const float*)d_in[6];
    const float* w_w  = (const float*)d_in[7];
    const float* w_b  = (const float*)d_in[8];
    const float* bn_g = (const float*)d_in[9];
    const float* bn_b = (const float*)d_in[10];

    const size_t G_OFF  = 0;
    const size_t FP_OFF = 33554432;
    const size_t WY_OFF = 33554432;          // aliases FP (dead after softmax)
    const size_t P_OFF  = 100663296;
    const size_t ST_OFF = 101711872;
    const size_t WB_OFF = 101713920;
    const size_t NEEDED = 102107136;
    if (ws_size < NEEDED) return;

    char* ws = (char*)d_ws;
    u16t*  g_buf = (u16t*)(ws + G_OFF);
    float* fp    = (float*)(ws + FP_OFF);
    u16t*  wy    = (u16t*)(ws + WY_OFF);
    u16t*  p_buf = (u16t*)(ws + P_OFF);
    float* stats = (float*)(ws + ST_OFF);
    u16t*  wb    = (u16t*)(ws + WB_OFF);

    float* th_g = (float*)d_out;             // theta fp32 (16.78M floats)
    float* ph_g = th_g + 16777216;           // phi fp32
    u16t*  y_buf = (u16t*)d_out;             // y bf16 (reuses d_out after QK)

    k_prep<<<128, 256, 0, stream>>>(g_w, t_w, p_w, w_w, wb, stats);
    k_proj<<<2048, 512, 0, stream>>>(x, wb, t_b, p_b, g_b, th_g, ph_g, g_buf);
    k_qk<<<512, 256, 0, stream>>>(th_g, ph_g, fp);
    k_softmax<<<512, 256, 0, stream>>>(fp, p_buf);
    k_pv<<<1024, 512, 0, stream>>>(p_buf, g_buf, y_buf);
    k_wconv<<<2048, 256, 0, stream>>>(y_buf, wb, w_b, wy, stats);
    k_final<<<2048, 256, 0, stream>>>(wy, x, stats, bn_g, bn_b, (float*)d_out);
}